// Round 8
// baseline (220.762 us; speedup 1.0000x reference)
//
#include <hip/hip_runtime.h>
#include <hip/hip_bf16.h>
#include <stdint.h>

#define N_LGN   17400
#define N_POST  50000
#define NNZ     800000
#define N_BASIS 5
#define ELL_CAP 48

#define NBKT      196        // row buckets of 256 rows (50000/256 -> 196)
#define CAPB      5120       // per-bucket edge capacity (mean 4082, +16 sigma)
#define BIN_CHUNK 4096
#define BIN_BLOCKS ((NNZ + BIN_CHUNK - 1) / BIN_CHUNK)          // 196

#define TPOSE_CBLK   32
#define TPOSE_BLOCKS ((N_LGN + TPOSE_CBLK - 1) / TPOSE_CBLK)    // 544

// ---- non-temporal load/store helpers (clang ext_vector types; HIP int2/4 are structs) ---
typedef int   ivec2 __attribute__((ext_vector_type(2)));
typedef int   ivec4 __attribute__((ext_vector_type(4)));
typedef float fvec2 __attribute__((ext_vector_type(2)));
__device__ __forceinline__ int2 ntload_i2(const int2* p) {
    ivec2 v = __builtin_nontemporal_load((const ivec2*)p);
    return make_int2(v.x, v.y);
}
__device__ __forceinline__ int4 ntload_i4(const int4* p) {
    ivec4 v = __builtin_nontemporal_load((const ivec4*)p);
    return make_int4(v.x, v.y, v.z, v.w);
}
__device__ __forceinline__ float ntload_f(const float* p) { return __builtin_nontemporal_load(p); }
__device__ __forceinline__ int   ntload_i(const int* p)   { return __builtin_nontemporal_load(p); }
__device__ __forceinline__ void ntstore_i2(int2* p, int2 v) {
    ivec2 t; t.x = v.x; t.y = v.y;
    __builtin_nontemporal_store(t, (ivec2*)p);
}
__device__ __forceinline__ void ntstore_i4(int4* p, int4 v) {
    ivec4 t; t.x = v.x; t.y = v.y; t.z = v.z; t.w = v.w;
    __builtin_nontemporal_store(t, (ivec4*)p);
}
__device__ __forceinline__ void ntstore_f2(float2* p, float2 v) {
    fvec2 t; t.x = v.x; t.y = v.y;
    __builtin_nontemporal_store(t, (fvec2*)p);
}

// ---------------- fused prep: bin edges (blocks [0,196)) + transpose (blocks [196,740)) --
// All global reads here are read-once streams and all writes are write-once streams ->
// non-temporal, so they don't evict xTb from L2 (xTb is what k_compute_ell gathers from).
__global__ __launch_bounds__(256) void k_prep(const float* __restrict__ inp,
                                              __hip_bfloat162* __restrict__ xTb,
                                              const int2* __restrict__ idx2,
                                              const float* __restrict__ w,
                                              const int* __restrict__ syn,
                                              int* __restrict__ bucketCnt,
                                              int2* __restrict__ bEdges) {
    __shared__ alignas(16) int2 ebuf[BIN_CHUNK];       // 32KB (transpose aliases tile here)
    __shared__ unsigned char sbuf[BIN_CHUNK];          // bucket id per buffer slot
    __shared__ int hcnt[256], hstart[256], hcur[256], gbase[256];
    int tid = threadIdx.x;
    if (blockIdx.x < BIN_BLOCKS) {
        int base = blockIdx.x * BIN_CHUNK;
        int ne = NNZ - base; if (ne > BIN_CHUNK) ne = BIN_CHUNK;
        hcnt[tid] = 0;
        __syncthreads();
        int2 pk[16]; int bk[16];
#pragma unroll
        for (int i = 0; i < 16; ++i) {
            int p = i * 256 + tid;
            bk[i] = -1;
            if (p < ne) {
                int2 rc = ntload_i2(&idx2[base + p]);      // (row, col) coalesced, streaming
                float wv = ntload_f(&w[base + p]);
                int sy = ntload_i(&syn[base + p]);
                int b  = rc.x >> 8;
                int rl = rc.x & 255;
                pk[i] = make_int2(rc.y | (sy << 15) | (rl << 19), __float_as_int(wv));
                bk[i] = b;
                atomicAdd(&hcnt[b], 1);                    // LDS histogram
            }
        }
        __syncthreads();
        int v = hcnt[tid];
        hstart[tid] = v;
        __syncthreads();
        for (int off = 1; off < 256; off <<= 1) {
            int t = (tid >= off) ? hstart[tid - off] : 0;
            __syncthreads();
            hstart[tid] += t;
            __syncthreads();
        }
        int excl = hstart[tid] - v;
        hstart[tid] = excl;
        hcur[tid]  = excl;
        if (tid < NBKT) gbase[tid] = atomicAdd(&bucketCnt[tid], v);  // one atomic per bucket
        __syncthreads();
#pragma unroll
        for (int i = 0; i < 16; ++i) {
            if (bk[i] >= 0) {
                int pos = atomicAdd(&hcur[bk[i]], 1);      // place, grouped by bucket
                ebuf[pos] = pk[i];
                sbuf[pos] = (unsigned char)bk[i];
            }
        }
        __syncthreads();
        for (int p = tid; p < ne; p += 256) {              // flush: contiguous runs per bucket
            int b  = sbuf[p];
            int gi = gbase[b] + (p - hstart[b]);
            if (gi < CAPB) ntstore_i2(&bEdges[b * CAPB + gi], ebuf[p]);
        }
    } else {
        // ---- transpose x (128 x 17400) fp32 -> xTb (17400 x 64) bf16x2, 32-col tiles ----
        float* tile = (float*)ebuf;                        // 32*129*4 = 16,512B <= 32KB
        int c0 = (blockIdx.x - BIN_BLOCKS) * TPOSE_CBLK;
        for (int it = 0; it < 16; ++it) {
            int flat = it * 256 + tid;
            int s  = flat >> 5;
            int cl = flat & 31;
            int c  = c0 + cl;
            float v = 0.0f;
            if (c < N_LGN) v = ntload_f(&inp[s * N_LGN + c]);  // read-once stream
            tile[cl * 129 + s] = v;
        }
        __syncthreads();
        for (int it = 0; it < 8; ++it) {
            int flat = it * 256 + tid;
            int cl = flat >> 6;
            int sp = flat & 63;
            int c  = c0 + cl;
            if (c < N_LGN) {
                float2 f = make_float2(tile[cl * 129 + 2 * sp], tile[cl * 129 + 2 * sp + 1]);
                xTb[c * 64 + sp] = __float22bfloat162_rn(f);   // cached: hot data
            }
        }
    }
}

// ---------------- build ELL from binned edges: all writes full-line coalesced ------------
// Slab is ZERO-INITIALIZED (col=0, w=0) so ELL pad slots are exact-zero edges: the compute
// kernel can run uniform padded loops with no per-row tail handling (pad contributes 0.0).
// bEdges read and ell write are both streams -> non-temporal.
__global__ __launch_bounds__(512) void k_build(const int2* __restrict__ bEdges,
                                               const int* __restrict__ bucketCnt,
                                               int2* __restrict__ ell,
                                               int* __restrict__ counts) {
    __shared__ alignas(16) int2 slab[256 * ELL_CAP];   // 98,304B: 256 rows x 48 slots
    __shared__ int rcnt[256];
    int tid = threadIdx.x;
    int b   = blockIdx.x;
    if (tid < 256) rcnt[tid] = 0;
    {   // zero-fill slab (24 int4 stores/thread)
        int4* s4w = (int4*)slab;
        for (int i = tid; i < 256 * ELL_CAP / 2; i += 512) s4w[i] = make_int4(0, 0, 0, 0);
    }
    __syncthreads();
    int cnt = bucketCnt[b]; if (cnt > CAPB) cnt = CAPB;
    for (int p = tid; p < cnt; p += 512) {
        int2 e = ntload_i2(&bEdges[b * CAPB + p]);     // coalesced streaming read
        int rl = (e.x >> 19) & 0xFF;
        int r = atomicAdd(&rcnt[rl], 1);               // LDS atomic: cheap
        if (r < ELL_CAP)
            slab[rl * ELL_CAP + r] =
                make_int2((e.x & 0x7FFF) | (((e.x >> 15) & 0xF) << 16), e.y);
    }
    __syncthreads();
    const int4* s4 = (const int4*)slab;                // slab -> global, full lines
    int4* e4 = (int4*)(ell + (size_t)b * (256 * ELL_CAP));
    for (int i = tid; i < 256 * ELL_CAP / 2; i += 512) ntstore_i4(&e4[i], s4[i]);
    if (tid < 256) {
        int row = b * 256 + tid;
        if (row < N_POST) counts[row] = rcnt[tid];
    }
}

// ---------------- CSR fallback path (used only if ws too small for ELL) ----------------
__global__ __launch_bounds__(256) void k_transpose_bf16(const float* __restrict__ inp,
                                                        __hip_bfloat162* __restrict__ xTb) {
    __shared__ float tile[64 * 129];
    int c0  = blockIdx.x * 64;
    int tid = threadIdx.x;
    for (int it = 0; it < 32; ++it) {
        int flat = it * 256 + tid;
        int s  = flat >> 6;
        int cl = flat & 63;
        int c  = c0 + cl;
        float v = 0.0f;
        if (c < N_LGN) v = inp[s * N_LGN + c];
        tile[cl * 129 + s] = v;
    }
    __syncthreads();
    for (int it = 0; it < 16; ++it) {
        int flat = it * 256 + tid;
        int cl = flat >> 6;
        int sp = flat & 63;
        int c  = c0 + cl;
        if (c < N_LGN) {
            float2 f = make_float2(tile[cl * 129 + 2 * sp], tile[cl * 129 + 2 * sp + 1]);
            xTb[c * 64 + sp] = __float22bfloat162_rn(f);
        }
    }
}

__global__ __launch_bounds__(256) void k_hist(const int4* __restrict__ idx2,
                                              int* __restrict__ counts) {
    int t = blockIdx.x * 256 + threadIdx.x;
    if (t >= NNZ / 2) return;
    int4 rc = idx2[t];
    atomicAdd(&counts[rc.x], 1);
    atomicAdd(&counts[rc.z], 1);
}

__global__ __launch_bounds__(1024) void k_scan1(const int* __restrict__ counts,
                                                int* __restrict__ rowStart,
                                                int* __restrict__ blockSums) {
    __shared__ int tmp[1024];
    int tid = threadIdx.x;
    int gid = blockIdx.x * 1024 + tid;
    int v = (gid < N_POST) ? counts[gid] : 0;
    tmp[tid] = v;
    __syncthreads();
    for (int off = 1; off < 1024; off <<= 1) {
        int t = (tid >= off) ? tmp[tid - off] : 0;
        __syncthreads();
        tmp[tid] += t;
        __syncthreads();
    }
    if (gid < N_POST) rowStart[gid] = tmp[tid] - v;
    if (tid == 1023) blockSums[blockIdx.x] = tmp[1023];
}

__global__ __launch_bounds__(64) void k_scan2(const int* __restrict__ blockSums,
                                              int* __restrict__ blockOffsets, int nblk) {
    __shared__ int tmp[64];
    int tid = threadIdx.x;
    int v = (tid < nblk) ? blockSums[tid] : 0;
    tmp[tid] = v;
    __syncthreads();
    for (int off = 1; off < 64; off <<= 1) {
        int t = (tid >= off) ? tmp[tid - off] : 0;
        __syncthreads();
        tmp[tid] += t;
        __syncthreads();
    }
    if (tid < nblk) blockOffsets[tid] = tmp[tid] - v;
}

__global__ __launch_bounds__(1024) void k_scan3(int* __restrict__ rowStart,
                                                const int* __restrict__ blockOffsets) {
    int gid = blockIdx.x * 1024 + threadIdx.x;
    if (gid < N_POST) rowStart[gid] += blockOffsets[blockIdx.x];
}

__global__ __launch_bounds__(256) void k_scatter_csr(const int4* __restrict__ idx2,
                                                     const float2* __restrict__ w2,
                                                     const int2* __restrict__ syn2,
                                                     const int* __restrict__ rowStart,
                                                     int* __restrict__ cursor,
                                                     int2* __restrict__ edges) {
    int t = blockIdx.x * 256 + threadIdx.x;
    if (t >= NNZ / 2) return;
    int4 rc = idx2[t];
    float2 ww = w2[t];
    int2 sy = syn2[t];
    int p0 = rowStart[rc.x] + atomicAdd(&cursor[rc.x], 1);
    edges[p0] = make_int2(rc.y | (sy.x << 16), __float_as_int(ww.x));
    int p1 = rowStart[rc.z] + atomicAdd(&cursor[rc.z], 1);
    edges[p1] = make_int2(rc.w | (sy.y << 16), __float_as_int(ww.y));
}

// per-edge FMA body into named accumulator arrays
#define EDGE_FMA2(P0, P1, XW, FA, F4)                                             \
    P0[0] = fmaf((XW).x, (FA).x, P0[0]); P1[0] = fmaf((XW).y, (FA).x, P1[0]);     \
    P0[1] = fmaf((XW).x, (FA).y, P0[1]); P1[1] = fmaf((XW).y, (FA).y, P1[1]);     \
    P0[2] = fmaf((XW).x, (FA).z, P0[2]); P1[2] = fmaf((XW).y, (FA).z, P1[2]);     \
    P0[3] = fmaf((XW).x, (FA).w, P0[3]); P1[3] = fmaf((XW).y, (FA).w, P1[3]);     \
    P0[4] = fmaf((XW).x, (F4),   P0[4]); P1[4] = fmaf((XW).y, (F4),   P1[4]);

// factor-read + scale + FMA for one stream (consumes already-gathered x)
#define FINISH_STREAM(P0, P1, X, EX, EY)                                          \
    {                                                                             \
        int sy_  = (EX) >> 16;                                                    \
        float w_ = __int_as_float(EY);                                            \
        float4 fA_ = *(const float4*)&facsP[sy_ * 8];                             \
        float  f4_ = facsP[sy_ * 8 + 4];                                          \
        float2 xw_ = make_float2((X).x * w_, (X).y * w_);                         \
        EDGE_FMA2(P0, P1, xw_, fA_, f4_)                                          \
    }

// ---------------- main compute (ELL): 16 rows/block, 2 rows/wave, low-VGPR ---------------
// Cache policy: xTb gathers CACHED (the 4.45MB hot set we want resident in L2); ell
// staging loads and out2 stores NON-TEMPORAL so the 19MB + 125MB streams don't evict it.
// Pad slots are exact zeros (k_build) so the loop is uniform to max(cntA,cntB).
__global__ __launch_bounds__(512, 8) void k_compute_ell(const __hip_bfloat162* __restrict__ xTb,
                                                        const int2* __restrict__ ell,
                                                        const int* __restrict__ counts,
                                                        const float* __restrict__ sw,
                                                        float2* __restrict__ out2) {
    __shared__ alignas(16) float facsP[80];          // synaptic_weights 10x5, padded to 10x8
    __shared__ float accLds[40 * 133];               // reused for both 8-row phases
    __shared__ alignas(16) int2 eLds[16 * ELL_CAP];  // 16 rows x 48 slots = 6144B
    int tid  = threadIdx.x;
    int wave = tid >> 6;
    int lane = tid & 63;
    int n0   = blockIdx.x * 16;                      // 3125*16 == 50000 exactly

    if (tid < 50) facsP[(tid / 5) * 8 + (tid % 5)] = sw[tid];
    if (tid < 16 * ELL_CAP / 2)                      // 384 threads x int4 = 6144B coalesced
        ((int4*)eLds)[tid] = ntload_i4(&((const int4*)(ell + (size_t)n0 * ELL_CAP))[tid]);
    int cA = counts[n0 + wave];     if (cA > ELL_CAP) cA = ELL_CAP;
    int cB = counts[n0 + 8 + wave]; if (cB > ELL_CAP) cB = ELL_CAP;
    __syncthreads();

    float aA0[N_BASIS] = {0.f, 0.f, 0.f, 0.f, 0.f};
    float aA1[N_BASIS] = {0.f, 0.f, 0.f, 0.f, 0.f};
    float aB0[N_BASIS] = {0.f, 0.f, 0.f, 0.f, 0.f};
    float aB1[N_BASIS] = {0.f, 0.f, 0.f, 0.f, 0.f};

    const int4* epA = (const int4*)(eLds + wave * ELL_CAP);        // 2 edges per int4
    const int4* epB = (const int4*)(eLds + (wave + 8) * ELL_CAP);
    int mc = cA > cB ? cA : cB;
    for (int j = 0; j < mc; j += 2) {
        int h = j >> 1;
        int4 A = epA[h];                             // row A edges j, j+1
        int4 B = epB[h];                             // row B edges j, j+1
        // 4 independent gathers issued back-to-back (256B/wave each, coalesced, CACHED)
        float2 xA0 = __bfloat1622float2(xTb[(A.x & 0xFFFF) * 64 + lane]);
        float2 xA1 = __bfloat1622float2(xTb[(A.z & 0xFFFF) * 64 + lane]);
        float2 xB0 = __bfloat1622float2(xTb[(B.x & 0xFFFF) * 64 + lane]);
        float2 xB1 = __bfloat1622float2(xTb[(B.z & 0xFFFF) * 64 + lane]);
        // per-stream finish: one fA live at a time
        FINISH_STREAM(aA0, aA1, xA0, A.x, A.y)
        FINISH_STREAM(aA0, aA1, xA1, A.z, A.w)
        FINISH_STREAM(aB0, aB1, xB0, B.x, B.y)
        FINISH_STREAM(aB0, aB1, xB1, B.z, B.w)
    }

    int base2 = blockIdx.x * 40;                     // 16 rows x 5 = 80 floats = 40 float2/s
    // ---- phase A: rows n0..n0+7 ----
#pragma unroll
    for (int r = 0; r < N_BASIS; ++r) {
        int jj = wave * 5 + r;
        accLds[jj * 133 + 2 * lane]     = aA0[r];
        accLds[jj * 133 + 2 * lane + 1] = aA1[r];
    }
    __syncthreads();
    for (int it = 0; it < 5; ++it) {
        int flat = it * 512 + tid;                   // 0..2559
        int s  = flat / 20;
        int jj = flat % 20;
        float f0 = accLds[(2 * jj) * 133 + s];
        float f1 = accLds[(2 * jj + 1) * 133 + s];
        ntstore_f2(&out2[s * 125000 + base2 + jj], make_float2(f0, f1));
    }
    __syncthreads();                                 // WAR: all reads done before reuse
    // ---- phase B: rows n0+8..n0+15 ----
#pragma unroll
    for (int r = 0; r < N_BASIS; ++r) {
        int jj = wave * 5 + r;
        accLds[jj * 133 + 2 * lane]     = aB0[r];
        accLds[jj * 133 + 2 * lane + 1] = aB1[r];
    }
    __syncthreads();
    for (int it = 0; it < 5; ++it) {
        int flat = it * 512 + tid;
        int s  = flat / 20;
        int jj = flat % 20;
        float f0 = accLds[(2 * jj) * 133 + s];
        float f1 = accLds[(2 * jj + 1) * 133 + s];
        ntstore_f2(&out2[s * 125000 + base2 + 20 + jj], make_float2(f0, f1));
    }
}

// ---------------- CSR-fallback compute: one wave per row (safety path) ------------------
__global__ __launch_bounds__(512, 8) void k_compute(const __hip_bfloat162* __restrict__ xTb,
                                                    const int2* __restrict__ edges,
                                                    const int* __restrict__ rowStart,
                                                    const int* __restrict__ counts,
                                                    const float* __restrict__ sw,
                                                    float2* __restrict__ out2) {
    __shared__ alignas(16) float facsP[80];
    __shared__ float accLds[40 * 133];
    int tid  = threadIdx.x;
    int wave = tid >> 6;
    int lane = tid & 63;
    int n    = blockIdx.x * 8 + wave;
    int cnt  = counts[n];

    if (tid < 50) facsP[(tid / 5) * 8 + (tid % 5)] = sw[tid];
    __syncthreads();

    float a0[N_BASIS] = {0.f, 0.f, 0.f, 0.f, 0.f};
    float a1[N_BASIS] = {0.f, 0.f, 0.f, 0.f, 0.f};

    const int2* ep = edges + rowStart[n];
    int j = 0;
    for (; j + 1 < cnt; j += 2) {
        int2 e0 = ep[j];
        int2 e1 = ep[j + 1];
        float2 x0 = __bfloat1622float2(xTb[(e0.x & 0xFFFF) * 64 + lane]);
        float2 x1 = __bfloat1622float2(xTb[(e1.x & 0xFFFF) * 64 + lane]);
        FINISH_STREAM(a0, a1, x0, e0.x, e0.y)
        FINISH_STREAM(a0, a1, x1, e1.x, e1.y)
    }
    if (j < cnt) {
        int2 e0 = ep[j];
        float2 x0 = __bfloat1622float2(xTb[(e0.x & 0xFFFF) * 64 + lane]);
        FINISH_STREAM(a0, a1, x0, e0.x, e0.y)
    }

#pragma unroll
    for (int r = 0; r < N_BASIS; ++r) {
        int jj = wave * 5 + r;
        accLds[jj * 133 + 2 * lane]     = a0[r];
        accLds[jj * 133 + 2 * lane + 1] = a1[r];
    }
    __syncthreads();

    int base2 = blockIdx.x * 20;
    for (int it = 0; it < 5; ++it) {
        int flat = it * 512 + tid;
        int s  = flat / 20;
        int jj = flat % 20;
        float f0 = accLds[(2 * jj) * 133 + s];
        float f1 = accLds[(2 * jj + 1) * 133 + s];
        ntstore_f2(&out2[s * 125000 + base2 + jj], make_float2(f0, f1));
    }
}

// ---------------- launcher ----------------
extern "C" void kernel_launch(void* const* d_in, const int* in_sizes, int n_in,
                              void* d_out, int out_size, void* d_ws, size_t ws_size,
                              hipStream_t stream) {
    const float* inp     = (const float*)d_in[0];   // (1,128,17400) fp32
    const int*   indices = (const int*)d_in[1];     // (800000,2)
    const float* weights = (const float*)d_in[2];   // (800000,)
    const float* sw      = (const float*)d_in[3];   // (10,5)
    const int*   syn     = (const int*)d_in[4];     // (800000,)

    char* ws = (char*)d_ws;
    __hip_bfloat162* xTb = (__hip_bfloat162*)(ws);          // 17400*64*4 = 4,454,400 B
    int* counts          = (int*)(ws + 4454400);            // 200,000 B

    const size_t ELL_BYTES_END = 4654400ULL + (size_t)N_POST * ELL_CAP * 8;  // 23,854,400
    bool useEll = (ws_size >= ELL_BYTES_END);

    if (useEll) {
        int2* ell = (int2*)(ws + 4654400);                  // 19,200,000 B (16B aligned)
        // d_out (128MB) doubles as scratch until k_compute_ell's epilogue overwrites it:
        int2* bEdges   = (int2*)d_out;                      // 196*5120*8 = 8,028,160 B
        int*  bucketCnt = (int*)((char*)d_out + (size_t)NBKT * CAPB * 8);  // 784 B
        hipMemsetAsync(bucketCnt, 0, 1024, stream);
        k_prep<<<BIN_BLOCKS + TPOSE_BLOCKS, 256, 0, stream>>>(
            inp, xTb, (const int2*)indices, weights, syn, bucketCnt, bEdges);
        k_build<<<NBKT, 512, 0, stream>>>(bEdges, bucketCnt, ell, counts);
        k_compute_ell<<<N_POST / 16, 512, 0, stream>>>(xTb, ell, counts, sw,
                                                       (float2*)d_out);
    } else {
        int* cursor    = (int*)(ws + 4654400);              // 200,000 B (adjacent to counts)
        int* rowStart  = (int*)(ws + 4854400);              // 200,000 B
        int* blockSums = (int*)(ws + 5054400);              // 256 B
        int* blockOffs = (int*)(ws + 5054656);              // 256 B
        int2* edges    = (int2*)(ws + 5054912);             // 6,400,000 B
        hipMemsetAsync(counts, 0, 400000, stream);          // counts + cursor
        k_transpose_bf16<<<(N_LGN + 63) / 64, 256, 0, stream>>>(inp, xTb);
        k_hist<<<(NNZ / 2 + 255) / 256, 256, 0, stream>>>((const int4*)indices, counts);
        k_scan1<<<(N_POST + 1023) / 1024, 1024, 0, stream>>>(counts, rowStart, blockSums);
        k_scan2<<<1, 64, 0, stream>>>(blockSums, blockOffs, (N_POST + 1023) / 1024);
        k_scan3<<<(N_POST + 1023) / 1024, 1024, 0, stream>>>(rowStart, blockOffs);
        k_scatter_csr<<<(NNZ / 2 + 255) / 256, 256, 0, stream>>>(
            (const int4*)indices, (const float2*)weights, (const int2*)syn,
            rowStart, cursor, edges);
        k_compute<<<N_POST / 8, 512, 0, stream>>>(xTb, edges, rowStart, counts, sw,
                                                  (float2*)d_out);
    }
}

// Round 9
// 203.261 us; speedup vs baseline: 1.0861x; 1.0861x over previous
//
#include <hip/hip_runtime.h>
#include <hip/hip_bf16.h>
#include <stdint.h>

#define N_LGN   17400
#define N_POST  50000
#define NNZ     800000
#define N_BASIS 5
#define ELL_CAP 48

#define NBKT      196        // row buckets of 256 rows (50000/256 -> 196) for binning
#define NBKT_H    391        // half-buckets of 128 rows for k_build ((50000+127)/128)
#define CAPB      5120       // per-bucket edge capacity (mean 4082, +16 sigma)
#define BIN_CHUNK 4096
#define BIN_BLOCKS ((NNZ + BIN_CHUNK - 1) / BIN_CHUNK)          // 196

#define TPOSE_CBLK   32
#define TPOSE_BLOCKS ((N_LGN + TPOSE_CBLK - 1) / TPOSE_CBLK)    // 544

// ---------------- fused prep: bin edges (blocks [0,196)) + transpose (blocks [196,740)) --
__global__ __launch_bounds__(256) void k_prep(const float* __restrict__ inp,
                                              __hip_bfloat162* __restrict__ xTb,
                                              const int2* __restrict__ idx2,
                                              const float* __restrict__ w,
                                              const int* __restrict__ syn,
                                              int* __restrict__ bucketCnt,
                                              int2* __restrict__ bEdges) {
    __shared__ alignas(16) int2 ebuf[BIN_CHUNK];       // 32KB (transpose aliases tile here)
    __shared__ unsigned char sbuf[BIN_CHUNK];          // bucket id per buffer slot
    __shared__ int hcnt[256], hstart[256], hcur[256], gbase[256];
    int tid = threadIdx.x;
    if (blockIdx.x < BIN_BLOCKS) {
        int base = blockIdx.x * BIN_CHUNK;
        int ne = NNZ - base; if (ne > BIN_CHUNK) ne = BIN_CHUNK;
        hcnt[tid] = 0;
        __syncthreads();
        int2 pk[16]; int bk[16];
#pragma unroll
        for (int i = 0; i < 16; ++i) {
            int p = i * 256 + tid;
            bk[i] = -1;
            if (p < ne) {
                int2 rc = idx2[base + p];                  // (row, col) coalesced
                float wv = w[base + p];
                int sy = syn[base + p];
                int b  = rc.x >> 8;
                int rl = rc.x & 255;
                pk[i] = make_int2(rc.y | (sy << 15) | (rl << 19), __float_as_int(wv));
                bk[i] = b;
                atomicAdd(&hcnt[b], 1);                    // LDS histogram
            }
        }
        __syncthreads();
        int v = hcnt[tid];
        hstart[tid] = v;
        __syncthreads();
        for (int off = 1; off < 256; off <<= 1) {
            int t = (tid >= off) ? hstart[tid - off] : 0;
            __syncthreads();
            hstart[tid] += t;
            __syncthreads();
        }
        int excl = hstart[tid] - v;
        hstart[tid] = excl;
        hcur[tid]  = excl;
        if (tid < NBKT) gbase[tid] = atomicAdd(&bucketCnt[tid], v);  // one atomic per bucket
        __syncthreads();
#pragma unroll
        for (int i = 0; i < 16; ++i) {
            if (bk[i] >= 0) {
                int pos = atomicAdd(&hcur[bk[i]], 1);      // place, grouped by bucket
                ebuf[pos] = pk[i];
                sbuf[pos] = (unsigned char)bk[i];
            }
        }
        __syncthreads();
        for (int p = tid; p < ne; p += 256) {              // flush: contiguous runs per bucket
            int b  = sbuf[p];
            int gi = gbase[b] + (p - hstart[b]);
            if (gi < CAPB) bEdges[b * CAPB + gi] = ebuf[p];
        }
    } else {
        // ---- transpose x (128 x 17400) fp32 -> xTb (17400 x 64) bf16x2, 32-col tiles ----
        float* tile = (float*)ebuf;                        // 32*129*4 = 16,512B <= 32KB
        int c0 = (blockIdx.x - BIN_BLOCKS) * TPOSE_CBLK;
        for (int it = 0; it < 16; ++it) {
            int flat = it * 256 + tid;
            int s  = flat >> 5;
            int cl = flat & 31;
            int c  = c0 + cl;
            float v = 0.0f;
            if (c < N_LGN) v = inp[s * N_LGN + c];
            tile[cl * 129 + s] = v;
        }
        __syncthreads();
        for (int it = 0; it < 8; ++it) {
            int flat = it * 256 + tid;
            int cl = flat >> 6;
            int sp = flat & 63;
            int c  = c0 + cl;
            if (c < N_LGN) {
                float2 f = make_float2(tile[cl * 129 + 2 * sp], tile[cl * 129 + 2 * sp + 1]);
                xTb[c * 64 + sp] = __float22bfloat162_rn(f);
            }
        }
    }
}

// ---------------- build ELL from binned edges: half-bucket blocks for occupancy ----------
// 128-row half-buckets: LDS slab 49,152B -> 3 blocks/CU (was 98KB -> 1 block/CU), 391
// blocks (was 196). Each half-block re-reads its source bucket's edges and filters by
// row range (+6.4MB reads total, ~1us — cheap for 2x parallelism and half the serial
// zero-fill/copy-out per block). Slab zero-init keeps ELL pad slots exact-zero edges.
__global__ __launch_bounds__(512) void k_build(const int2* __restrict__ bEdges,
                                               const int* __restrict__ bucketCnt,
                                               int2* __restrict__ ell,
                                               int* __restrict__ counts) {
    __shared__ alignas(16) int2 slab[128 * ELL_CAP];   // 49,152B: 128 rows x 48 slots
    __shared__ int rcnt[128];
    int tid   = threadIdx.x;
    int hb    = blockIdx.x;            // half-bucket id, rows [hb*128, hb*128+128)
    int B     = hb >> 1;               // source bucket in bEdges (256 rows)
    int rbase = (hb & 1) << 7;         // row-low offset within the bucket
    if (tid < 128) rcnt[tid] = 0;
    {   // zero-fill slab (12 int4 stores/thread)
        int4* s4w = (int4*)slab;
        for (int i = tid; i < 128 * ELL_CAP / 2; i += 512) s4w[i] = make_int4(0, 0, 0, 0);
    }
    __syncthreads();
    int cnt = bucketCnt[B]; if (cnt > CAPB) cnt = CAPB;
    for (int p = tid; p < cnt; p += 512) {
        int2 e = bEdges[B * CAPB + p];                 // coalesced read
        int rl = (e.x >> 19) & 0xFF;
        int r2 = rl - rbase;
        if ((unsigned)r2 < 128u) {
            int r = atomicAdd(&rcnt[r2], 1);           // LDS atomic: cheap
            if (r < ELL_CAP)
                slab[r2 * ELL_CAP + r] =
                    make_int2((e.x & 0x7FFF) | (((e.x >> 15) & 0xF) << 16), e.y);
        }
    }
    __syncthreads();
    int row0  = hb << 7;
    int nrows = N_POST - row0; if (nrows > 128) nrows = 128;
    if (nrows <= 0) return;
    const int4* s4 = (const int4*)slab;                // slab -> global, full lines
    int4* e4 = (int4*)(ell + (size_t)row0 * ELL_CAP);
    int n4 = nrows * ELL_CAP / 2;
    for (int i = tid; i < n4; i += 512) e4[i] = s4[i];
    if (tid < nrows) counts[row0 + tid] = rcnt[tid];
}

// ---------------- CSR fallback path (used only if ws too small for ELL) ----------------
__global__ __launch_bounds__(256) void k_transpose_bf16(const float* __restrict__ inp,
                                                        __hip_bfloat162* __restrict__ xTb) {
    __shared__ float tile[64 * 129];
    int c0  = blockIdx.x * 64;
    int tid = threadIdx.x;
    for (int it = 0; it < 32; ++it) {
        int flat = it * 256 + tid;
        int s  = flat >> 6;
        int cl = flat & 63;
        int c  = c0 + cl;
        float v = 0.0f;
        if (c < N_LGN) v = inp[s * N_LGN + c];
        tile[cl * 129 + s] = v;
    }
    __syncthreads();
    for (int it = 0; it < 16; ++it) {
        int flat = it * 256 + tid;
        int cl = flat >> 6;
        int sp = flat & 63;
        int c  = c0 + cl;
        if (c < N_LGN) {
            float2 f = make_float2(tile[cl * 129 + 2 * sp], tile[cl * 129 + 2 * sp + 1]);
            xTb[c * 64 + sp] = __float22bfloat162_rn(f);
        }
    }
}

__global__ __launch_bounds__(256) void k_hist(const int4* __restrict__ idx2,
                                              int* __restrict__ counts) {
    int t = blockIdx.x * 256 + threadIdx.x;
    if (t >= NNZ / 2) return;
    int4 rc = idx2[t];
    atomicAdd(&counts[rc.x], 1);
    atomicAdd(&counts[rc.z], 1);
}

__global__ __launch_bounds__(1024) void k_scan1(const int* __restrict__ counts,
                                                int* __restrict__ rowStart,
                                                int* __restrict__ blockSums) {
    __shared__ int tmp[1024];
    int tid = threadIdx.x;
    int gid = blockIdx.x * 1024 + tid;
    int v = (gid < N_POST) ? counts[gid] : 0;
    tmp[tid] = v;
    __syncthreads();
    for (int off = 1; off < 1024; off <<= 1) {
        int t = (tid >= off) ? tmp[tid - off] : 0;
        __syncthreads();
        tmp[tid] += t;
        __syncthreads();
    }
    if (gid < N_POST) rowStart[gid] = tmp[tid] - v;
    if (tid == 1023) blockSums[blockIdx.x] = tmp[1023];
}

__global__ __launch_bounds__(64) void k_scan2(const int* __restrict__ blockSums,
                                              int* __restrict__ blockOffsets, int nblk) {
    __shared__ int tmp[64];
    int tid = threadIdx.x;
    int v = (tid < nblk) ? blockSums[tid] : 0;
    tmp[tid] = v;
    __syncthreads();
    for (int off = 1; off < 64; off <<= 1) {
        int t = (tid >= off) ? tmp[tid - off] : 0;
        __syncthreads();
        tmp[tid] += t;
        __syncthreads();
    }
    if (tid < nblk) blockOffsets[tid] = tmp[tid] - v;
}

__global__ __launch_bounds__(1024) void k_scan3(int* __restrict__ rowStart,
                                                const int* __restrict__ blockOffsets) {
    int gid = blockIdx.x * 1024 + threadIdx.x;
    if (gid < N_POST) rowStart[gid] += blockOffsets[blockIdx.x];
}

__global__ __launch_bounds__(256) void k_scatter_csr(const int4* __restrict__ idx2,
                                                     const float2* __restrict__ w2,
                                                     const int2* __restrict__ syn2,
                                                     const int* __restrict__ rowStart,
                                                     int* __restrict__ cursor,
                                                     int2* __restrict__ edges) {
    int t = blockIdx.x * 256 + threadIdx.x;
    if (t >= NNZ / 2) return;
    int4 rc = idx2[t];
    float2 ww = w2[t];
    int2 sy = syn2[t];
    int p0 = rowStart[rc.x] + atomicAdd(&cursor[rc.x], 1);
    edges[p0] = make_int2(rc.y | (sy.x << 16), __float_as_int(ww.x));
    int p1 = rowStart[rc.z] + atomicAdd(&cursor[rc.z], 1);
    edges[p1] = make_int2(rc.w | (sy.y << 16), __float_as_int(ww.y));
}

// per-edge FMA body into named accumulator arrays
#define EDGE_FMA2(P0, P1, XW, FA, F4)                                             \
    P0[0] = fmaf((XW).x, (FA).x, P0[0]); P1[0] = fmaf((XW).y, (FA).x, P1[0]);     \
    P0[1] = fmaf((XW).x, (FA).y, P0[1]); P1[1] = fmaf((XW).y, (FA).y, P1[1]);     \
    P0[2] = fmaf((XW).x, (FA).z, P0[2]); P1[2] = fmaf((XW).y, (FA).z, P1[2]);     \
    P0[3] = fmaf((XW).x, (FA).w, P0[3]); P1[3] = fmaf((XW).y, (FA).w, P1[3]);     \
    P0[4] = fmaf((XW).x, (F4),   P0[4]); P1[4] = fmaf((XW).y, (F4),   P1[4]);

// factor-read + scale + FMA for one stream (consumes already-gathered x)
#define FINISH_STREAM(P0, P1, X, EX, EY)                                          \
    {                                                                             \
        int sy_  = (EX) >> 16;                                                    \
        float w_ = __int_as_float(EY);                                            \
        float4 fA_ = *(const float4*)&facsP[sy_ * 8];                             \
        float  f4_ = facsP[sy_ * 8 + 4];                                          \
        float2 xw_ = make_float2((X).x * w_, (X).y * w_);                         \
        EDGE_FMA2(P0, P1, xw_, fA_, f4_)                                          \
    }

// ---------------- main compute (ELL): 16 rows/block, 2 rows/wave, low-VGPR ---------------
// (round-7 proven version, byte-identical)
__global__ __launch_bounds__(512, 8) void k_compute_ell(const __hip_bfloat162* __restrict__ xTb,
                                                        const int2* __restrict__ ell,
                                                        const int* __restrict__ counts,
                                                        const float* __restrict__ sw,
                                                        float2* __restrict__ out2) {
    __shared__ alignas(16) float facsP[80];          // synaptic_weights 10x5, padded to 10x8
    __shared__ float accLds[40 * 133];               // reused for both 8-row phases
    __shared__ alignas(16) int2 eLds[16 * ELL_CAP];  // 16 rows x 48 slots = 6144B
    int tid  = threadIdx.x;
    int wave = tid >> 6;
    int lane = tid & 63;
    int n0   = blockIdx.x * 16;                      // 3125*16 == 50000 exactly

    if (tid < 50) facsP[(tid / 5) * 8 + (tid % 5)] = sw[tid];
    if (tid < 16 * ELL_CAP / 2)                      // 384 threads x int4 = 6144B coalesced
        ((int4*)eLds)[tid] = ((const int4*)(ell + (size_t)n0 * ELL_CAP))[tid];
    int cA = counts[n0 + wave];     if (cA > ELL_CAP) cA = ELL_CAP;
    int cB = counts[n0 + 8 + wave]; if (cB > ELL_CAP) cB = ELL_CAP;
    __syncthreads();

    float aA0[N_BASIS] = {0.f, 0.f, 0.f, 0.f, 0.f};
    float aA1[N_BASIS] = {0.f, 0.f, 0.f, 0.f, 0.f};
    float aB0[N_BASIS] = {0.f, 0.f, 0.f, 0.f, 0.f};
    float aB1[N_BASIS] = {0.f, 0.f, 0.f, 0.f, 0.f};

    const int4* epA = (const int4*)(eLds + wave * ELL_CAP);        // 2 edges per int4
    const int4* epB = (const int4*)(eLds + (wave + 8) * ELL_CAP);
    int mc = cA > cB ? cA : cB;
    for (int j = 0; j < mc; j += 2) {
        int h = j >> 1;
        int4 A = epA[h];                             // row A edges j, j+1
        int4 B = epB[h];                             // row B edges j, j+1
        // 4 independent gathers issued back-to-back (256B/wave each, coalesced)
        float2 xA0 = __bfloat1622float2(xTb[(A.x & 0xFFFF) * 64 + lane]);
        float2 xA1 = __bfloat1622float2(xTb[(A.z & 0xFFFF) * 64 + lane]);
        float2 xB0 = __bfloat1622float2(xTb[(B.x & 0xFFFF) * 64 + lane]);
        float2 xB1 = __bfloat1622float2(xTb[(B.z & 0xFFFF) * 64 + lane]);
        // per-stream finish: one fA live at a time
        FINISH_STREAM(aA0, aA1, xA0, A.x, A.y)
        FINISH_STREAM(aA0, aA1, xA1, A.z, A.w)
        FINISH_STREAM(aB0, aB1, xB0, B.x, B.y)
        FINISH_STREAM(aB0, aB1, xB1, B.z, B.w)
    }

    int base2 = blockIdx.x * 40;                     // 16 rows x 5 = 80 floats = 40 float2/s
    // ---- phase A: rows n0..n0+7 ----
#pragma unroll
    for (int r = 0; r < N_BASIS; ++r) {
        int jj = wave * 5 + r;
        accLds[jj * 133 + 2 * lane]     = aA0[r];
        accLds[jj * 133 + 2 * lane + 1] = aA1[r];
    }
    __syncthreads();
    for (int it = 0; it < 5; ++it) {
        int flat = it * 512 + tid;                   // 0..2559
        int s  = flat / 20;
        int jj = flat % 20;
        float f0 = accLds[(2 * jj) * 133 + s];
        float f1 = accLds[(2 * jj + 1) * 133 + s];
        out2[s * 125000 + base2 + jj] = make_float2(f0, f1);
    }
    __syncthreads();                                 // WAR: all reads done before reuse
    // ---- phase B: rows n0+8..n0+15 ----
#pragma unroll
    for (int r = 0; r < N_BASIS; ++r) {
        int jj = wave * 5 + r;
        accLds[jj * 133 + 2 * lane]     = aB0[r];
        accLds[jj * 133 + 2 * lane + 1] = aB1[r];
    }
    __syncthreads();
    for (int it = 0; it < 5; ++it) {
        int flat = it * 512 + tid;
        int s  = flat / 20;
        int jj = flat % 20;
        float f0 = accLds[(2 * jj) * 133 + s];
        float f1 = accLds[(2 * jj + 1) * 133 + s];
        out2[s * 125000 + base2 + 20 + jj] = make_float2(f0, f1);
    }
}

// ---------------- CSR-fallback compute: one wave per row (safety path) ------------------
__global__ __launch_bounds__(512, 8) void k_compute(const __hip_bfloat162* __restrict__ xTb,
                                                    const int2* __restrict__ edges,
                                                    const int* __restrict__ rowStart,
                                                    const int* __restrict__ counts,
                                                    const float* __restrict__ sw,
                                                    float2* __restrict__ out2) {
    __shared__ alignas(16) float facsP[80];
    __shared__ float accLds[40 * 133];
    int tid  = threadIdx.x;
    int wave = tid >> 6;
    int lane = tid & 63;
    int n    = blockIdx.x * 8 + wave;
    int cnt  = counts[n];

    if (tid < 50) facsP[(tid / 5) * 8 + (tid % 5)] = sw[tid];
    __syncthreads();

    float a0[N_BASIS] = {0.f, 0.f, 0.f, 0.f, 0.f};
    float a1[N_BASIS] = {0.f, 0.f, 0.f, 0.f, 0.f};

    const int2* ep = edges + rowStart[n];
    int j = 0;
    for (; j + 1 < cnt; j += 2) {
        int2 e0 = ep[j];
        int2 e1 = ep[j + 1];
        float2 x0 = __bfloat1622float2(xTb[(e0.x & 0xFFFF) * 64 + lane]);
        float2 x1 = __bfloat1622float2(xTb[(e1.x & 0xFFFF) * 64 + lane]);
        FINISH_STREAM(a0, a1, x0, e0.x, e0.y)
        FINISH_STREAM(a0, a1, x1, e1.x, e1.y)
    }
    if (j < cnt) {
        int2 e0 = ep[j];
        float2 x0 = __bfloat1622float2(xTb[(e0.x & 0xFFFF) * 64 + lane]);
        FINISH_STREAM(a0, a1, x0, e0.x, e0.y)
    }

#pragma unroll
    for (int r = 0; r < N_BASIS; ++r) {
        int jj = wave * 5 + r;
        accLds[jj * 133 + 2 * lane]     = a0[r];
        accLds[jj * 133 + 2 * lane + 1] = a1[r];
    }
    __syncthreads();

    int base2 = blockIdx.x * 20;
    for (int it = 0; it < 5; ++it) {
        int flat = it * 512 + tid;
        int s  = flat / 20;
        int jj = flat % 20;
        float f0 = accLds[(2 * jj) * 133 + s];
        float f1 = accLds[(2 * jj + 1) * 133 + s];
        out2[s * 125000 + base2 + jj] = make_float2(f0, f1);
    }
}

// ---------------- launcher ----------------
extern "C" void kernel_launch(void* const* d_in, const int* in_sizes, int n_in,
                              void* d_out, int out_size, void* d_ws, size_t ws_size,
                              hipStream_t stream) {
    const float* inp     = (const float*)d_in[0];   // (1,128,17400) fp32
    const int*   indices = (const int*)d_in[1];     // (800000,2)
    const float* weights = (const float*)d_in[2];   // (800000,)
    const float* sw      = (const float*)d_in[3];   // (10,5)
    const int*   syn     = (const int*)d_in[4];     // (800000,)

    char* ws = (char*)d_ws;
    __hip_bfloat162* xTb = (__hip_bfloat162*)(ws);          // 17400*64*4 = 4,454,400 B
    int* counts          = (int*)(ws + 4454400);            // 200,000 B

    const size_t ELL_BYTES_END = 4654400ULL + (size_t)N_POST * ELL_CAP * 8;  // 23,854,400
    bool useEll = (ws_size >= ELL_BYTES_END);

    if (useEll) {
        int2* ell = (int2*)(ws + 4654400);                  // 19,200,000 B (16B aligned)
        // d_out (128MB) doubles as scratch until k_compute_ell's epilogue overwrites it:
        int2* bEdges   = (int2*)d_out;                      // 196*5120*8 = 8,028,160 B
        int*  bucketCnt = (int*)((char*)d_out + (size_t)NBKT * CAPB * 8);  // 784 B
        hipMemsetAsync(bucketCnt, 0, 1024, stream);
        k_prep<<<BIN_BLOCKS + TPOSE_BLOCKS, 256, 0, stream>>>(
            inp, xTb, (const int2*)indices, weights, syn, bucketCnt, bEdges);
        k_build<<<NBKT_H, 512, 0, stream>>>(bEdges, bucketCnt, ell, counts);
        k_compute_ell<<<N_POST / 16, 512, 0, stream>>>(xTb, ell, counts, sw,
                                                       (float2*)d_out);
    } else {
        int* cursor    = (int*)(ws + 4654400);              // 200,000 B (adjacent to counts)
        int* rowStart  = (int*)(ws + 4854400);              // 200,000 B
        int* blockSums = (int*)(ws + 5054400);              // 256 B
        int* blockOffs = (int*)(ws + 5054656);              // 256 B
        int2* edges    = (int2*)(ws + 5054912);             // 6,400,000 B
        hipMemsetAsync(counts, 0, 400000, stream);          // counts + cursor
        k_transpose_bf16<<<(N_LGN + 63) / 64, 256, 0, stream>>>(inp, xTb);
        k_hist<<<(NNZ / 2 + 255) / 256, 256, 0, stream>>>((const int4*)indices, counts);
        k_scan1<<<(N_POST + 1023) / 1024, 1024, 0, stream>>>(counts, rowStart, blockSums);
        k_scan2<<<1, 64, 0, stream>>>(blockSums, blockOffs, (N_POST + 1023) / 1024);
        k_scan3<<<(N_POST + 1023) / 1024, 1024, 0, stream>>>(rowStart, blockOffs);
        k_scatter_csr<<<(NNZ / 2 + 255) / 256, 256, 0, stream>>>(
            (const int4*)indices, (const float2*)weights, (const int2*)syn,
            rowStart, cursor, edges);
        k_compute<<<N_POST / 8, 512, 0, stream>>>(xTb, edges, rowStart, counts, sw,
                                                  (float2*)d_out);
    }
}